// Round 4
// baseline (9507.037 us; speedup 1.0000x reference)
//
#include <hip/hip_runtime.h>
#include <cstdint>
#include <cstddef>

#define SEQ 4096
#define HID 512
#define NTHETA 5
#define NBLK 16
#define RPB 32                  // rows per block (NBLK*RPB == HID)
#define SENT_BITS 0x40000000u   // 2.0f — |tanh| < 1, so never a real h value

__device__ __forceinline__ float tanh_fast(float x) {
  x = fminf(fmaxf(x, -20.0f), 20.0f);
  const float e = __expf(2.0f * x);
  return (e - 1.0f) / (e + 1.0f);
}

// C[4096,512] = act(A[4096,K] @ W[512,K]^T + bias + noise_plane)
__global__ __launch_bounds__(256) void gemm_bias_noise(
    const float* __restrict__ A, const float* __restrict__ W,
    const float* __restrict__ bias, const float* __restrict__ noise,
    float* __restrict__ C, int K, int doTanh)
{
  const int N = HID;
  const int bm = blockIdx.y, bn = blockIdx.x;
  const int tid = threadIdx.x;
  const int tx = tid & 15, ty = tid >> 4;
  const int row0 = bm * 64, col0 = bn * 64;
  __shared__ float As[16][68];
  __shared__ float Ws[16][68];
  float acc[4][4] = {{0.f, 0.f, 0.f, 0.f}, {0.f, 0.f, 0.f, 0.f},
                     {0.f, 0.f, 0.f, 0.f}, {0.f, 0.f, 0.f, 0.f}};
  const int lrow = tid >> 2, lkq = tid & 3;
  for (int kt = 0; kt < K; kt += 16) {
    const float4 av = *(const float4*)&A[(size_t)(row0 + lrow) * K + kt + lkq * 4];
    const float4 wv = *(const float4*)&W[(size_t)(col0 + lrow) * K + kt + lkq * 4];
    __syncthreads();
    As[lkq * 4 + 0][lrow] = av.x; As[lkq * 4 + 1][lrow] = av.y;
    As[lkq * 4 + 2][lrow] = av.z; As[lkq * 4 + 3][lrow] = av.w;
    Ws[lkq * 4 + 0][lrow] = wv.x; Ws[lkq * 4 + 1][lrow] = wv.y;
    Ws[lkq * 4 + 2][lrow] = wv.z; Ws[lkq * 4 + 3][lrow] = wv.w;
    __syncthreads();
#pragma unroll
    for (int k = 0; k < 16; ++k) {
      const float4 a = *(const float4*)&As[k][ty * 4];
      const float4 bq = *(const float4*)&Ws[k][tx * 4];
      const float a4[4] = {a.x, a.y, a.z, a.w};
      const float b4[4] = {bq.x, bq.y, bq.z, bq.w};
#pragma unroll
      for (int i = 0; i < 4; ++i)
#pragma unroll
        for (int j = 0; j < 4; ++j)
          acc[i][j] = fmaf(a4[i], b4[j], acc[i][j]);
    }
  }
  const float4 bv = *(const float4*)&bias[col0 + tx * 4];
#pragma unroll
  for (int i = 0; i < 4; ++i) {
    const int row = row0 + ty * 4 + i;
    const float4 nv = *(const float4*)&noise[(size_t)row * N + col0 + tx * 4];
    float4 o;
    o.x = acc[i][0] + bv.x + nv.x;
    o.y = acc[i][1] + bv.y + nv.y;
    o.z = acc[i][2] + bv.z + nv.z;
    o.w = acc[i][3] + bv.w + nv.w;
    if (doTanh) {
      o.x = tanh_fast(o.x); o.y = tanh_fast(o.y);
      o.z = tanh_fast(o.z); o.w = tanh_fast(o.w);
    }
    *(float4*)&C[(size_t)row * N + col0 + tx * 4] = o;
  }
}

// Pre-fill the h-exchange buffer (= out plane 0) with the sentinel bits.
__global__ void fill_sentinel(uint4* __restrict__ p, int n4) {
  const int i = blockIdx.x * blockDim.x + threadIdx.x;
  if (i < n4) p[i] = make_uint4(SENT_BITS, SENT_BITS, SENT_BITS, SENT_BITS);
}

// Sequential scan: h_t = tanh(drive_t + W_hh @ h_{t-1}).
// 16 blocks x 1024 thr; block owns 32 rows. Thread (r = tid>>5, s = tid&31)
// holds W[base+r, s+32k] (k<16) in regs. 512 loader threads poll one h value
// each (sentinel data-poll, 1x redundancy) into double-buffered LDS; one
// barrier per step; stride-32 broadcast ds_reads (conflict-free); 5-shuffle
// reduce; lane s==0 stores through the exchange plane (= out plane 0 / hs).
__global__ __launch_bounds__(1024) void recurrence(
    const float* __restrict__ Whh, const float* __restrict__ drive,
    const float* __restrict__ h0, unsigned* __restrict__ hexch)
{
  const int base = blockIdx.x * RPB;
  const int tid = threadIdx.x;
  const int s = tid & 31;        // h-slice id (stride-32)
  const int r = tid >> 5;        // local row 0..31
  const int row = base + r;

  __shared__ float hbuf[2][HID];

  // W slice -> 16 registers (strided gather; one-time)
  float w[16];
#pragma unroll
  for (int k = 0; k < 16; ++k)
    w[k] = Whh[(size_t)row * HID + s + 32 * k];

  for (int t = 0; t < SEQ; ++t) {
    float drv = 0.f;
    if (s == 0) drv = drive[(size_t)t * HID + row];  // issues before the spin

    float* buf = hbuf[t & 1];
    if (tid < HID) {
      float v;
      if (t == 0) {
        v = h0[tid];
      } else {
        const unsigned* src = &hexch[(size_t)(t - 1) * HID + tid];
        unsigned u;
        do {
          u = __hip_atomic_load(src, __ATOMIC_RELAXED,
                                __HIP_MEMORY_SCOPE_AGENT);
        } while (u == SENT_BITS);
        v = __uint_as_float(u);
      }
      buf[tid] = v;
    }
    __syncthreads();   // buf[t&1] ready; skew <= 1 step => other buffer

    float a0 = 0.f, a1 = 0.f, a2 = 0.f, a3 = 0.f;
#pragma unroll
    for (int k = 0; k < 16; k += 4) {
      a0 = fmaf(w[k + 0], buf[s + 32 * (k + 0)], a0);
      a1 = fmaf(w[k + 1], buf[s + 32 * (k + 1)], a1);
      a2 = fmaf(w[k + 2], buf[s + 32 * (k + 2)], a2);
      a3 = fmaf(w[k + 3], buf[s + 32 * (k + 3)], a3);
    }
    float sum = (a0 + a1) + (a2 + a3);
#pragma unroll
    for (int off = 1; off < 32; off <<= 1)
      sum += __shfl_xor(sum, off, 64);

    if (s == 0) {
      const float y = tanh_fast(sum + drv);
      __hip_atomic_store(&hexch[(size_t)t * HID + row], __float_as_uint(y),
                         __ATOMIC_RELAXED, __HIP_MEMORY_SCOPE_AGENT);
    }
  }
}

__global__ void copy_final(const float* __restrict__ src, float* __restrict__ dst) {
  dst[threadIdx.x] = src[threadIdx.x];
}

extern "C" void kernel_launch(void* const* d_in, const int* in_sizes, int n_in,
                              void* d_out, int out_size, void* d_ws, size_t ws_size,
                              hipStream_t stream) {
  const float* input    = (const float*)d_in[0];
  const float* internal = (const float*)d_in[1];
  const float* state    = (const float*)d_in[2];
  const float* W_ih     = (const float*)d_in[3];
  const float* W_hh     = (const float*)d_in[4];
  const float* bias     = (const float*)d_in[5];
  float* out = (float*)d_out;

  const size_t plane = (size_t)SEQ * HID;
  // hexch IS out plane 0 (hs): prefilled with sentinel, every element
  // overwritten exactly once by the recurrence.
  unsigned* hexch = (unsigned*)out;
  float*    drive = out + 5 * plane;   // rewritten by theta-GEMM k=4 afterwards

  fill_sentinel<<<(SEQ * HID / 4 + 255) / 256, 256, 0, stream>>>(
      (uint4*)hexch, SEQ * HID / 4);

  dim3 gg(HID / 64, SEQ / 64);
  // drive = x @ W_ih^T + b + internal[0]   (no tanh)
  gemm_bias_noise<<<gg, 256, 0, stream>>>(input, W_ih, bias, internal, drive,
                                          HID, 0);
  // hs (out plane 0, via sentinel exchange)
  recurrence<<<NBLK, 1024, 0, stream>>>(W_hh, drive, state, hexch);
  // theta rollouts: plane k -> plane k+1
  for (int k = 0; k < NTHETA; ++k) {
    gemm_bias_noise<<<gg, 256, 0, stream>>>(out + (size_t)k * plane, W_hh, bias,
                                            internal + (size_t)(k + 1) * plane,
                                            out + (size_t)(k + 1) * plane,
                                            HID, 1);
  }
  // final_state = hs[4095]
  copy_final<<<1, HID, 0, stream>>>(out + (size_t)4095 * HID, out + 6 * plane);
}